// Round 4
// baseline (1245.120 us; speedup 1.0000x reference)
//
#include <hip/hip_runtime.h>
#include <cstddef>

// Problem dims
#define BATCH 64
#define SEQ   256
#define VOCAB 50000
#define DIM   300
#define NW    8192
#define CLEN  16
#define CDIM  30
#define CHC   30
#define HID   128
#define NT    17
#define IN0   (DIM + CHC)   // 330
#define IN0P  336           // padded to multiple of 16
#define IN1   (2 * HID)     // 256
#define NPOS  (BATCH * SEQ) // 16384

// Workspace layout (floats)
constexpr size_t SZ_XG    = 2ull * BATCH * SEQ * 384;    // 12,582,912
constexpr size_t SZ_TEXTS = (size_t)NPOS * IN0P;         // 5,505,024 (aliased as h0 after GEMM0)
constexpr size_t SZ_H1    = (size_t)NPOS * 256;          // 4,194,304
constexpr size_t SZ_TOK   = 245792;                      // (NW+1)*30 rounded
constexpr size_t SZ_EMIS  = (size_t)NPOS * NT;           // 278,528
constexpr size_t SZ_WPAD  = 768ull * IN0P;               // 258,048
constexpr size_t OFF_XG    = 0;
constexpr size_t OFF_TEXTS = OFF_XG + SZ_XG;
constexpr size_t OFF_H1    = OFF_TEXTS + SZ_TEXTS;
constexpr size_t OFF_TOK   = OFF_H1 + SZ_H1;
constexpr size_t OFF_EMIS  = OFF_TOK + SZ_TOK;
constexpr size_t OFF_WPAD  = OFF_EMIS + SZ_EMIS;
constexpr size_t OFF_LLH   = OFF_WPAD + SZ_WPAD;

__device__ __forceinline__ float sigm(float x) {
    return 1.f / (1.f + __expf(-x));
}
__device__ __forceinline__ float tanh_fast(float x) {
    x = fminf(fmaxf(x, -15.f), 15.f);
    float e = __expf(-2.f * x);
    return (1.f - e) / (1.f + e);
}
__device__ __forceinline__ float dot4(float4 a, float4 b) {
    return a.x * b.x + a.y * b.y + a.z * b.z + a.w * b.w;
}
__device__ __forceinline__ float getc(float4 v, int c) {
    return c == 0 ? v.x : c == 1 ? v.y : c == 2 ? v.z : v.w;
}
// Sum across the 4 lanes of a quad using DPP quad_perm (VALU-only).
__device__ __forceinline__ float quad_sum(float x) {
    int y = __builtin_amdgcn_update_dpp(0, __float_as_int(x), 0xB1, 0xF, 0xF, false); // [1,0,3,2]
    x += __int_as_float(y);
    y = __builtin_amdgcn_update_dpp(0, __float_as_int(x), 0x4E, 0xF, 0xF, false);     // [2,3,0,1]
    x += __int_as_float(y);
    return x;
}
// add partner lane (7 - (lane&7))'s value via DPP ROW_HALF_MIRROR (0x141).
// Pure VALU: replaces the ds_swizzle xor-4 (LDS pipe + ~120cy latency + the
// 524288 bank-conflict counts observed in round 2).
__device__ __forceinline__ float mirror8_add(float x) {
    int y = __builtin_amdgcn_update_dpp(0, __float_as_int(x), 0x141, 0xF, 0xF, false);
    return x + __int_as_float(y);
}

// ---------------- K1: char CNN + relu + maxpool -> tok_enc[(n+1)][30] ----
__global__ __launch_bounds__(256) void char_conv_k(
    const float* __restrict__ char_emb,  // [500][30]
    const float* __restrict__ conv_w,    // [30][30][3]
    const float* __restrict__ conv_b,    // [30]
    const int*   __restrict__ words,     // [8192][16]
    float* __restrict__ tok_enc)         // [8193][30]
{
    __shared__ __align__(16) float cs[8][CLEN][CDIM];
    __shared__ float wsm[CHC * CDIM * 3];
    __shared__ float bs[CHC];
    int n0 = blockIdx.x * 8;
    int tid = threadIdx.x;
    for (int e = tid; e < CHC * CDIM * 3; e += 256) wsm[e] = conv_w[e];
    if (tid < CHC) bs[tid] = conv_b[tid];
    for (int e = tid; e < 8 * CLEN * CDIM; e += 256) {
        int wi = e / (CLEN * CDIM);
        int rem = e - wi * (CLEN * CDIM);
        int l = rem / CDIM;
        int i = rem - l * CDIM;
        int ci = words[(n0 + wi) * CLEN + l];
        cs[wi][l][i] = char_emb[ci * CDIM + i];
    }
    __syncthreads();
    int wi = tid >> 5;
    int o = tid & 31;
    if (o < CHC) {
        float best = -1e30f;
        for (int l = 0; l < CLEN; l++) {
            float s = 0.f;
            #pragma unroll
            for (int k = 0; k < 3; k++) {
                int ll = l + k - 1;
                if (ll >= 0 && ll < CLEN) {
                    #pragma unroll
                    for (int i = 0; i < CDIM; i++)
                        s += cs[wi][ll][i] * wsm[(o * CDIM + i) * 3 + k];
                }
            }
            best = fmaxf(best, s);
        }
        tok_enc[(size_t)(n0 + wi + 1) * CDIM + o] = fmaxf(best + bs[o], 0.f);
    }
}

// ---------------- K2: texts = concat(word_emb[tok], tok_enc[widx]), pad to 336
__global__ __launch_bounds__(128) void build_texts_k(
    const float* __restrict__ word_emb,
    const float* __restrict__ tok_enc,
    const int*   __restrict__ tokens,
    const int*   __restrict__ widx,
    float* __restrict__ texts)
{
    int p = blockIdx.x;
    int tok = tokens[p];
    int ci = widx[p];
    float* o = texts + (size_t)p * IN0P;
    const float* wr = word_emb + (size_t)tok * DIM;
    const float* tr = tok_enc + (size_t)ci * CDIM;
    for (int c = threadIdx.x; c < IN0P; c += 128)
        o[c] = (c < DIM) ? wr[c] : (c < IN0 ? tr[c - DIM] : 0.f);
}

// ---------------- K2b: pad w_ih_l0 (768x330) -> (768x336) ---------------
__global__ __launch_bounds__(64) void pad_w_k(
    const float* __restrict__ w, float* __restrict__ wp)
{
    int r = blockIdx.x;
    for (int c = threadIdx.x; c < IN0P; c += 64)
        wp[(size_t)r * IN0P + c] = (c < IN0) ? w[(size_t)r * IN0 + c] : 0.f;
}

// ---------------- K3/K5: xg = A @ W_ih^T + b_ih, stored [d][b][t][g] -----
// A: [16384][K] row-major (K multiple of 16), W: [768][K] row-major
// v3b: W is NOT staged in LDS (each thread's 8 B-values are wave-duplicated
// 16-way; W is 1 MB = L2-resident, same-address lanes dedup at TA). Per 4
// k-steps each thread loads 8 float4 W-row chunks, double-buffered in
// registers. LDS holds only A (16 KB/block): 24 b128/CU/k-step = 288cy <
// 384cy VALU -> VALU-bound. v3 BUG FIX: k4body now takes the LOCAL LDS
// k-offset (0/4/8/12); v3 indexed As with the global k, reading far past
// the 16-row tile for it>=1 (the round-3 absmax failure).
#define GBM 128
#define GBN 128
#define GBK 16
__global__ __launch_bounds__(256, 3) void gemm_xg_k(
    const float* __restrict__ A,
    const float* __restrict__ W,
    const float* __restrict__ bias,
    float* __restrict__ out,
    int K)
{
    __shared__ __align__(16) float As[2][GBK][GBM];
    int tid = threadIdx.x;
    int B = blockIdx.y * gridDim.x + blockIdx.x;   // 0..767, gridDim.x = 6
    int X = B & 7;           // XCD (round-robin dispatch)
    int idx = B >> 3;        // 0..95 within XCD
    int mt = X * 16 + idx / 6;
    int nt = idx - (idx / 6) * 6;
    int n0 = nt * GBN;
    int m0 = mt * GBM;
    int lrow = tid >> 1;
    int lk = (tid & 1) * 8;
    int ty = tid >> 4;   // 0..15 (m)
    int tx = tid & 15;   // 0..15 (n)

    const float* ap = A + (size_t)(m0 + lrow) * K + lk;
    const float* wb2 = W + (size_t)64 * K;   // +64 rows
    int rowK[4];
    #pragma unroll
    for (int j = 0; j < 4; j++) rowK[j] = (n0 + tx * 4 + j) * K;

    float acc[8][8];
    #pragma unroll
    for (int i = 0; i < 8; i++)
        #pragma unroll
        for (int j = 0; j < 8; j++) acc[i][j] = 0.f;

    // stage A tile 0 into buffer 0
    {
        float4 a0 = *(const float4*)(ap);
        float4 a1 = *(const float4*)(ap + 4);
        float* as = &As[0][lk][lrow];   // element j at +j*GBM
        as[0*GBM] = a0.x; as[1*GBM] = a0.y; as[2*GBM] = a0.z; as[3*GBM] = a0.w;
        as[4*GBM] = a1.x; as[5*GBM] = a1.y; as[6*GBM] = a1.z; as[7*GBM] = a1.w;
    }
    // prefetch W chunk k=0..3 into wc
    float4 wc[8], wn[8];
    #pragma unroll
    for (int r = 0; r < 8; r++)
        wc[r] = *(const float4*)((r < 4 ? W : wb2) + rowK[r & 3]);
    __syncthreads();

    int nk = K / GBK;
    int cur = 0;

    // one 4-k-step group: consume WU (holds W[.][kglob..kglob+4) for the 8
    // n-rows), prefetch WL <- chunk at global k = knext, and do 4 rank-1
    // updates using LDS rows [kl, kl+4) of the CURRENT 16-row tile.
    auto k4body = [&](int kl, int knext, float4* WU, float4* WL) {
        #pragma unroll
        for (int r = 0; r < 8; r++)
            WL[r] = *(const float4*)((r < 4 ? W : wb2) + rowK[r & 3] + knext);
        #pragma unroll
        for (int kk = 0; kk < 4; kk++) {
            const float* asp = &As[cur][kl + kk][ty * 8];
            float4 va0 = *(const float4*)(asp);
            float4 va1 = *(const float4*)(asp + 4);
            float av[8] = {va0.x, va0.y, va0.z, va0.w, va1.x, va1.y, va1.z, va1.w};
            #pragma unroll
            for (int i = 0; i < 8; i++)
                #pragma unroll
                for (int r = 0; r < 8; r++)
                    acc[i][r] += av[i] * getc(WU[r], kk);
        }
    };

    for (int it = 0; it < nk - 1; it++) {
        // register-prefetch next A tile (hidden behind the 1024-FMA body)
        const float* apn = ap + (it + 1) * GBK;
        float4 na0 = *(const float4*)(apn);
        float4 na1 = *(const float4*)(apn + 4);
        int kb = it * GBK;
        k4body(0,  kb + 4,  wc, wn);
        k4body(4,  kb + 8,  wn, wc);
        k4body(8,  kb + 12, wc, wn);
        k4body(12, kb + 16, wn, wc);   // wc <- next tile chunk 0
        int nb = cur ^ 1;
        {
            float* as = &As[nb][lk][lrow];
            as[0*GBM] = na0.x; as[1*GBM] = na0.y; as[2*GBM] = na0.z; as[3*GBM] = na0.w;
            as[4*GBM] = na1.x; as[5*GBM] = na1.y; as[6*GBM] = na1.z; as[7*GBM] = na1.w;
        }
        __syncthreads();
        cur = nb;
    }
    {   // final tile: first three prefetches in-bounds; last is a dummy at k=0
        int kb = (nk - 1) * GBK;
        k4body(0,  kb + 4,  wc, wn);
        k4body(4,  kb + 8,  wn, wc);
        k4body(8,  kb + 12, wc, wn);
        k4body(12, 0,       wn, wc);
    }

    // store to xg layout: ((d*64+b)*256+t)*384 + g
    int c0 = n0 + tx * 4;
    int d = (c0 >= 384) ? 1 : 0;
    int g0 = c0 - d * 384;
    float4 bb0 = *(const float4*)(bias + c0);
    float4 bb1 = *(const float4*)(bias + c0 + 64);
    int mbase = m0 + ty * 8;
    #pragma unroll
    for (int i = 0; i < 8; i++) {
        int m = mbase + i;
        int b = m >> 8;
        int t = m & 255;
        float* op = out + (((size_t)(d * BATCH + b) * SEQ + t) * 384);
        float4 r0, r1;
        r0.x = acc[i][0] + bb0.x; r0.y = acc[i][1] + bb0.y;
        r0.z = acc[i][2] + bb0.z; r0.w = acc[i][3] + bb0.w;
        r1.x = acc[i][4] + bb1.x; r1.y = acc[i][5] + bb1.y;
        r1.z = acc[i][6] + bb1.z; r1.w = acc[i][7] + bb1.w;
        *(float4*)(op + g0) = r0;
        *(float4*)(op + g0 + 64) = r1;
    }
}

// ---------------- K4/K6: GRU recurrence, one wg per (dir, batch) ---------
// v3: thread (e2 = i>>3, c = i&7) covers TWO output rows e in {e2, e2+64}
// with a 16-float k-chunk [16c,16c+16). 32 ds_read_b128 per step (halved vs
// v1) and the 8-lane combine is now pure VALU: quad_sum (DPP) then
// ROW_HALF_MIRROR add (partner 7-c). Selection parity uses the gray code
// sel = (c^(c>>1))&1, which is invariant under c -> 7-c (mirror partner
// selects the same e), and sel(0)=0/sel(1)=1 keeps the c<2 h-store covering
// both e values. No LDS op in the reduce chain; LDS pipe/step = 384cy vs
// v1's 768, VALU unchanged -> expect ~VALU-bound.
__global__ __launch_bounds__(512, 2) void gru_rec_k(
    const float* __restrict__ xg,    // [2][64][256][384]
    const float* __restrict__ w_hh,  // [2][384][128]
    const float* __restrict__ b_hh,  // [2][384]
    const int*   __restrict__ lens,  // [64]
    float* __restrict__ out)         // [64][256][256], channel = d*128+j
{
    int d = blockIdx.x & 1;
    int b = blockIdx.x >> 1;
    int i = threadIdx.x;   // 0..511
    int c = i & 7;         // k-chunk: floats [16c, 16c+16)
    int e2 = i >> 3;       // 0..63
    int sel = (c ^ (c >> 1)) & 1;   // gray: invariant under c -> 7-c
    int eSel = e2 + 64 * sel;
    __shared__ __align__(16) float hS[2][HID];

    // rotated chunk order: slot j covers float4 index m = (j + (c>>1)) & 3
    int mj[4];
    #pragma unroll
    for (int j = 0; j < 4; j++) mj[j] = (j + (c >> 1)) & 3;

    const float* wb = w_hh + (size_t)d * 384 * HID;
    float4 wR0[4], wZ0[4], wN0[4], wR1[4], wZ1[4], wN1[4];
    #pragma unroll
    for (int j = 0; j < 4; j++) {
        int off = 16 * c + 4 * mj[j];
        wR0[j] = *(const float4*)(wb + (size_t)(e2)       * HID + off);
        wZ0[j] = *(const float4*)(wb + (size_t)(128 + e2) * HID + off);
        wN0[j] = *(const float4*)(wb + (size_t)(256 + e2) * HID + off);
        wR1[j] = *(const float4*)(wb + (size_t)(64 + e2)  * HID + off);
        wZ1[j] = *(const float4*)(wb + (size_t)(192 + e2) * HID + off);
        wN1[j] = *(const float4*)(wb + (size_t)(320 + e2) * HID + off);
    }
    float bhR = b_hh[d * 384 + eSel];
    float bhZ = b_hh[d * 384 + 128 + eSel];
    float bhN = b_hh[d * 384 + 256 + eSel];
    int len = lens[b];

    if (i < HID) hS[0][i] = 0.f;
    float hold = 0.f;
    __syncthreads();

    const float* xgb = xg + ((size_t)(d * BATCH + b)) * SEQ * 384;
    float* outb = out + (size_t)b * SEQ * 256 + d * HID;

    int t0 = d ? (SEQ - 1) : 0;
    float xvR = xgb[(size_t)t0 * 384 + eSel];
    float xvZ = xgb[(size_t)t0 * 384 + 128 + eSel];
    float xvN = xgb[(size_t)t0 * 384 + 256 + eSel];
    int tPrev = t0;

    // LDS float4 indices for the 4 rotated reads
    int idxA = c * 4 + mj[0];
    int idxB = c * 4 + mj[1];
    int idxC = c * 4 + mj[2];
    int idxD = c * 4 + mj[3];

    for (int s = 0; s < SEQ; s++) {
        int t = d ? (SEQ - 1 - s) : s;
        // deferred out-store of the previous step's h
        if (s && c < 2) outb[(size_t)tPrev * 256 + eSel] = hold;
        // prefetch next step's xg
        int sn = (s + 1 < SEQ) ? (s + 1) : s;
        int tn = d ? (SEQ - 1 - sn) : sn;
        float nxvR = xgb[(size_t)tn * 384 + eSel];
        float nxvZ = xgb[(size_t)tn * 384 + 128 + eSel];
        float nxvN = xgb[(size_t)tn * 384 + 256 + eSel];

        const float4* hb = (const float4*)hS[s & 1];
        float4 hv0 = hb[idxA];
        float4 hv1 = hb[idxB];
        float4 hv2 = hb[idxC];
        float4 hv3 = hb[idxD];

        float sR0 = dot4(wR0[0], hv0) + dot4(wR0[1], hv1) + dot4(wR0[2], hv2) + dot4(wR0[3], hv3);
        float sZ0 = dot4(wZ0[0], hv0) + dot4(wZ0[1], hv1) + dot4(wZ0[2], hv2) + dot4(wZ0[3], hv3);
        float sN0 = dot4(wN0[0], hv0) + dot4(wN0[1], hv1) + dot4(wN0[2], hv2) + dot4(wN0[3], hv3);
        float sR1 = dot4(wR1[0], hv0) + dot4(wR1[1], hv1) + dot4(wR1[2], hv2) + dot4(wR1[3], hv3);
        float sZ1 = dot4(wZ1[0], hv0) + dot4(wZ1[1], hv1) + dot4(wZ1[2], hv2) + dot4(wZ1[3], hv3);
        float sN1 = dot4(wN1[0], hv0) + dot4(wN1[1], hv1) + dot4(wN1[2], hv2) + dot4(wN1[3], hv3);

        // quad partials (each quad covers one 64-float half of k)
        sR0 = quad_sum(sR0); sZ0 = quad_sum(sZ0); sN0 = quad_sum(sN0);
        sR1 = quad_sum(sR1); sZ1 = quad_sum(sZ1); sN1 = quad_sum(sN1);
        // select this lane's e, then add partner half (lane 7-c, same sel)
        float sR = mirror8_add(sel ? sR1 : sR0);
        float sZ = mirror8_add(sel ? sZ1 : sZ0);
        float sN = mirror8_add(sel ? sN1 : sN0);

        float r = sigm(xvR + sR + bhR);
        float z = sigm(xvZ + sZ + bhZ);
        float n = tanh_fast(xvN + r * (sN + bhN));
        float hnew = (1.f - z) * n + z * hold;
        hold = (t < len) ? hnew : hold;
        if (c < 2) hS[(s & 1) ^ 1][eSel] = hold;
        tPrev = t;
        xvR = nxvR; xvZ = nxvZ; xvN = nxvN;
        __syncthreads();
    }
    if (c < 2) outb[(size_t)tPrev * 256 + eSel] = hold;
}

// ---------------- K7: MLP (relu) + emissions -----------------------------
__global__ __launch_bounds__(128) void mlp_emis_k(
    const float* __restrict__ h1,    // [16384][256]
    const float* __restrict__ w1,    // [256][128]
    const float* __restrict__ b1,    // [128]
    const float* __restrict__ w2,    // [128][17]
    const float* __restrict__ b2,    // [17]
    float* __restrict__ emis)        // [16384][17]
{
    __shared__ __align__(16) float hrow[8 * 256];
    __shared__ float hid[8][HID];
    int p0 = blockIdx.x * 8;
    int tid = threadIdx.x;
    for (int e = tid; e < 8 * 256; e += 128)
        hrow[e] = h1[(size_t)p0 * 256 + e];
    __syncthreads();
    float acc[8];
    float bb = b1[tid];
    #pragma unroll
    for (int i = 0; i < 8; i++) acc[i] = bb;
    for (int k = 0; k < 256; k++) {
        float wv = w1[k * HID + tid];
        #pragma unroll
        for (int i = 0; i < 8; i++) acc[i] += hrow[i * 256 + k] * wv;
    }
    #pragma unroll
    for (int i = 0; i < 8; i++) hid[i][tid] = fmaxf(acc[i], 0.f);
    __syncthreads();
    for (int idx = tid; idx < 8 * NT; idx += 128) {
        int pos = idx / NT;
        int tg = idx - pos * NT;
        float a = b2[tg];
        for (int k = 0; k < HID; k++) a += hid[pos][k] * w2[k * NT + tg];
        emis[(size_t)(p0 + pos) * NT + tg] = a;
    }
}

// ---------------- K8: CRF score + forward algorithm ----------------------
__global__ __launch_bounds__(64) void crf_k(
    const float* __restrict__ emis,   // [64][256][17]
    const float* __restrict__ start,
    const float* __restrict__ endv,
    const float* __restrict__ trans,  // [17][17]
    const int*   __restrict__ target, // [64][256]
    const int*   __restrict__ lens,
    float* __restrict__ llh)          // [64]
{
    int b = blockIdx.x;
    int tid = threadIdx.x;
    __shared__ float tr[NT * NT];
    __shared__ float aSh[NT];
    __shared__ float scoreSh;
    for (int e = tid; e < NT * NT; e += 64) tr[e] = trans[e];
    __syncthreads();
    int len = lens[b];
    const int* tgt = target + b * SEQ;
    const float* eb = emis + (size_t)b * SEQ * NT;

    // gold score (parallel over t, reduce in-wave)
    float part = 0.f;
    for (int t = 1 + tid; t < SEQ; t += 64) {
        if (t < len) {
            int tp = tgt[t - 1], tc = tgt[t];
            part += tr[tp * NT + tc] + eb[(size_t)t * NT + tc];
        }
    }
    #pragma unroll
    for (int off = 32; off > 0; off >>= 1)
        part += __shfl_down(part, off, 64);
    if (tid == 0) {
        int t0 = tgt[0];
        scoreSh = part + start[t0] + eb[t0] + endv[tgt[len - 1]];
    }

    // forward algorithm
    float a = (tid < NT) ? (start[tid] + eb[tid]) : 0.f;
    for (int t = 1; t < SEQ; t++) {
        if (tid < NT) aSh[tid] = a;
        __syncthreads();
        if (t < len && tid < NT) {
            float m = -1e30f;
            #pragma unroll
            for (int i = 0; i < NT; i++)
                m = fmaxf(m, aSh[i] + tr[i * NT + tid]);
            float ssum = 0.f;
            #pragma unroll
            for (int i = 0; i < NT; i++)
                ssum += __expf(aSh[i] + tr[i * NT + tid] - m);
            a = m + __logf(ssum) + eb[(size_t)t * NT + tid];
        }
        __syncthreads();
    }
    float v = (tid < NT) ? (a + endv[tid]) : -1e30f;
    float m = v;
    #pragma unroll
    for (int off = 32; off > 0; off >>= 1)
        m = fmaxf(m, __shfl_down(m, off, 64));
    m = __shfl(m, 0, 64);
    float e = (tid < NT) ? __expf(v - m) : 0.f;
    #pragma unroll
    for (int off = 32; off > 0; off >>= 1)
        e += __shfl_down(e, off, 64);
    if (tid == 0) {
        float logz = m + __logf(e);
        llh[b] = scoreSh - logz;
    }
}

// ---------------- K9: final loss -----------------------------------------
__global__ __launch_bounds__(64) void finalize_k(
    const float* __restrict__ llh,
    const int*   __restrict__ lens,
    float* __restrict__ out)
{
    int tid = threadIdx.x;
    float s = llh[tid];
    float lf = (float)lens[tid];
    #pragma unroll
    for (int off = 32; off > 0; off >>= 1) {
        s += __shfl_down(s, off, 64);
        lf += __shfl_down(lf, off, 64);
    }
    if (tid == 0) out[0] = -(s / lf);
}

extern "C" void kernel_launch(void* const* d_in, const int* in_sizes, int n_in,
                              void* d_out, int out_size, void* d_ws, size_t ws_size,
                              hipStream_t stream) {
    const float* char_emb = (const float*)d_in[0];
    const float* conv_w   = (const float*)d_in[1];
    const float* conv_b   = (const float*)d_in[2];
    const float* word_emb = (const float*)d_in[3];
    const float* w_ih_l0  = (const float*)d_in[4];
    const float* w_hh_l0  = (const float*)d_in[5];
    const float* b_ih_l0  = (const float*)d_in[6];
    const float* b_hh_l0  = (const float*)d_in[7];
    const float* w_ih_l1  = (const float*)d_in[8];
    const float* w_hh_l1  = (const float*)d_in[9];
    const float* b_ih_l1  = (const float*)d_in[10];
    const float* b_hh_l1  = (const float*)d_in[11];
    const float* mlp_w1   = (const float*)d_in[12];
    const float* mlp_b1   = (const float*)d_in[13];
    const float* mlp_w2   = (const float*)d_in[14];
    const float* mlp_b2   = (const float*)d_in[15];
    const float* crf_start= (const float*)d_in[16];
    const float* crf_end  = (const float*)d_in[17];
    const float* crf_trans= (const float*)d_in[18];
    const int* bcw   = (const int*)d_in[19];
    // d_in[20] batched_char_words_len: unused by reference
    const int* bcwi  = (const int*)d_in[21];
    const int* btok  = (const int*)d_in[22];
    const int* blen  = (const int*)d_in[23];
    const int* target= (const int*)d_in[24];

    float* ws    = (float*)d_ws;
    float* xg    = ws + OFF_XG;
    float* texts = ws + OFF_TEXTS;   // aliased: h0 overwrites texts after xg0 GEMM
    float* h0    = texts;
    float* h1    = ws + OFF_H1;
    float* tok   = ws + OFF_TOK;
    float* emis  = ws + OFF_EMIS;
    float* wpad  = ws + OFF_WPAD;
    float* llh   = ws + OFF_LLH;

    hipMemsetAsync(tok, 0, CDIM * sizeof(float), stream);  // tok_enc row 0 = zeros
    pad_w_k<<<768, 64, 0, stream>>>(w_ih_l0, wpad);
    char_conv_k<<<NW / 8, 256, 0, stream>>>(char_emb, conv_w, conv_b, bcw, tok);
    build_texts_k<<<NPOS, 128, 0, stream>>>(word_emb, tok, btok, bcwi, texts);
    gemm_xg_k<<<dim3(768 / GBN, NPOS / GBM), 256, 0, stream>>>(texts, wpad, b_ih_l0, xg, IN0P);
    gru_rec_k<<<2 * BATCH, 512, 0, stream>>>(xg, w_hh_l0, b_hh_l0, blen, h0);
    gemm_xg_k<<<dim3(768 / GBN, NPOS / GBM), 256, 0, stream>>>(h0, w_ih_l1, b_ih_l1, xg, IN1);
    gru_rec_k<<<2 * BATCH, 512, 0, stream>>>(xg, w_hh_l1, b_hh_l1, blen, h1);
    mlp_emis_k<<<NPOS / 8, 128, 0, stream>>>(h1, mlp_w1, mlp_b1, mlp_w2, mlp_b2, emis);
    crf_k<<<BATCH, 64, 0, stream>>>(emis, crf_start, crf_end, crf_trans, target, blen, llh);
    finalize_k<<<1, 64, 0, stream>>>(llh, blen, (float*)d_out);
}

// Round 5
// 925.836 us; speedup vs baseline: 1.3449x; 1.3449x over previous
//
#include <hip/hip_runtime.h>
#include <cstddef>

// Problem dims
#define BATCH 64
#define SEQ   256
#define VOCAB 50000
#define DIM   300
#define NW    8192
#define CLEN  16
#define CDIM  30
#define CHC   30
#define HID   128
#define NT    17
#define IN0   (DIM + CHC)   // 330
#define IN0P  336           // padded to multiple of 16
#define IN1   (2 * HID)     // 256
#define NPOS  (BATCH * SEQ) // 16384

// Workspace layout (floats)
constexpr size_t SZ_XG    = 2ull * BATCH * SEQ * 384;    // 12,582,912
constexpr size_t SZ_TEXTS = (size_t)NPOS * IN0P;         // 5,505,024 (aliased as h0 after GEMM0)
constexpr size_t SZ_H1    = (size_t)NPOS * 256;          // 4,194,304
constexpr size_t SZ_TOK   = 245792;                      // (NW+1)*30 rounded
constexpr size_t SZ_EMIS  = (size_t)NPOS * NT;           // 278,528
constexpr size_t SZ_WPAD  = 768ull * IN0P;               // 258,048
constexpr size_t OFF_XG    = 0;
constexpr size_t OFF_TEXTS = OFF_XG + SZ_XG;
constexpr size_t OFF_H1    = OFF_TEXTS + SZ_TEXTS;
constexpr size_t OFF_TOK   = OFF_H1 + SZ_H1;
constexpr size_t OFF_EMIS  = OFF_TOK + SZ_TOK;
constexpr size_t OFF_WPAD  = OFF_EMIS + SZ_EMIS;
constexpr size_t OFF_LLH   = OFF_WPAD + SZ_WPAD;

__device__ __forceinline__ float sigm(float x) {
    return 1.f / (1.f + __expf(-x));
}
__device__ __forceinline__ float tanh_fast(float x) {
    x = fminf(fmaxf(x, -15.f), 15.f);
    float e = __expf(-2.f * x);
    return (1.f - e) / (1.f + e);
}
__device__ __forceinline__ float dot4(float4 a, float4 b) {
    return a.x * b.x + a.y * b.y + a.z * b.z + a.w * b.w;
}
// Raw LDS-only barrier: __syncthreads() compiles to
// "s_waitcnt vmcnt(0) lgkmcnt(0); s_barrier" which DRAINS in-flight global
// loads/stores at every barrier (kills the xg prefetch / deferred-store
// pipeline: HBM latency ~600-900cy lands inside each GRU step). The only
// inter-wave data here flows through LDS, so lgkmcnt(0) alone is the
// correct fence; vmcnt ops stay in flight across the barrier.
__device__ __forceinline__ void lds_barrier() {
    asm volatile("s_waitcnt lgkmcnt(0)\n\ts_barrier" ::: "memory");
}
// Sum across the 4 lanes of a quad using DPP quad_perm (VALU-only).
__device__ __forceinline__ float quad_sum(float x) {
    int y = __builtin_amdgcn_update_dpp(0, __float_as_int(x), 0xB1, 0xF, 0xF, false); // [1,0,3,2]
    x += __int_as_float(y);
    y = __builtin_amdgcn_update_dpp(0, __float_as_int(x), 0x4E, 0xF, 0xF, false);     // [2,3,0,1]
    x += __int_as_float(y);
    return x;
}
// add partner lane (7 - (lane&7))'s value via DPP ROW_HALF_MIRROR (0x141).
__device__ __forceinline__ float mirror8_add(float x) {
    int y = __builtin_amdgcn_update_dpp(0, __float_as_int(x), 0x141, 0xF, 0xF, false);
    return x + __int_as_float(y);
}

// ---------------- K1: char CNN + relu + maxpool -> tok_enc[(n+1)][30] ----
__global__ __launch_bounds__(256) void char_conv_k(
    const float* __restrict__ char_emb,  // [500][30]
    const float* __restrict__ conv_w,    // [30][30][3]
    const float* __restrict__ conv_b,    // [30]
    const int*   __restrict__ words,     // [8192][16]
    float* __restrict__ tok_enc)         // [8193][30]
{
    __shared__ __align__(16) float cs[8][CLEN][CDIM];
    __shared__ float wsm[CHC * CDIM * 3];
    __shared__ float bs[CHC];
    int n0 = blockIdx.x * 8;
    int tid = threadIdx.x;
    for (int e = tid; e < CHC * CDIM * 3; e += 256) wsm[e] = conv_w[e];
    if (tid < CHC) bs[tid] = conv_b[tid];
    for (int e = tid; e < 8 * CLEN * CDIM; e += 256) {
        int wi = e / (CLEN * CDIM);
        int rem = e - wi * (CLEN * CDIM);
        int l = rem / CDIM;
        int i = rem - l * CDIM;
        int ci = words[(n0 + wi) * CLEN + l];
        cs[wi][l][i] = char_emb[ci * CDIM + i];
    }
    __syncthreads();
    int wi = tid >> 5;
    int o = tid & 31;
    if (o < CHC) {
        float best = -1e30f;
        for (int l = 0; l < CLEN; l++) {
            float s = 0.f;
            #pragma unroll
            for (int k = 0; k < 3; k++) {
                int ll = l + k - 1;
                if (ll >= 0 && ll < CLEN) {
                    #pragma unroll
                    for (int i = 0; i < CDIM; i++)
                        s += cs[wi][ll][i] * wsm[(o * CDIM + i) * 3 + k];
                }
            }
            best = fmaxf(best, s);
        }
        tok_enc[(size_t)(n0 + wi + 1) * CDIM + o] = fmaxf(best + bs[o], 0.f);
    }
}

// ---------------- K2: texts = concat(word_emb[tok], tok_enc[widx]), pad to 336
__global__ __launch_bounds__(128) void build_texts_k(
    const float* __restrict__ word_emb,
    const float* __restrict__ tok_enc,
    const int*   __restrict__ tokens,
    const int*   __restrict__ widx,
    float* __restrict__ texts)
{
    int p = blockIdx.x;
    int tok = tokens[p];
    int ci = widx[p];
    float* o = texts + (size_t)p * IN0P;
    const float* wr = word_emb + (size_t)tok * DIM;
    const float* tr = tok_enc + (size_t)ci * CDIM;
    for (int c = threadIdx.x; c < IN0P; c += 128)
        o[c] = (c < DIM) ? wr[c] : (c < IN0 ? tr[c - DIM] : 0.f);
}

// ---------------- K2b: pad w_ih_l0 (768x330) -> (768x336) ---------------
__global__ __launch_bounds__(64) void pad_w_k(
    const float* __restrict__ w, float* __restrict__ wp)
{
    int r = blockIdx.x;
    for (int c = threadIdx.x; c < IN0P; c += 64)
        wp[(size_t)r * IN0P + c] = (c < IN0) ? w[(size_t)r * IN0 + c] : 0.f;
}

// ---------------- K3/K5: xg = A @ W_ih^T + b_ih, stored [d][b][t][g] -----
// A: [16384][K] row-major (K multiple of 16), W: [768][K] row-major
// Round-2 structure (verified): LDS double-buffered A AND W (the round-4
// W-from-L2 variant was TA-request-bound: 16-address gathers, 331us), 1
// barrier per k-tile via lds_barrier (vmcnt stays in flight), register
// prefetch, conflict-free B fragments (tx*4 / 64+tx*4), XCD-bijective
// swizzle (768 = 8 XCD x 96; all 6 n-tiles of an A-tile land dispatch-
// adjacent on one XCD).
#define GBM 128
#define GBN 128
#define GBK 16
__global__ __launch_bounds__(256, 3) void gemm_xg_k(
    const float* __restrict__ A,
    const float* __restrict__ W,
    const float* __restrict__ bias,
    float* __restrict__ out,
    int K)
{
    __shared__ __align__(16) float As[2][GBK][GBM];
    __shared__ __align__(16) float Ws[2][GBK][GBN];
    int tid = threadIdx.x;
    int B = blockIdx.y * gridDim.x + blockIdx.x;   // 0..767, gridDim.x = 6
    int X = B & 7;           // XCD (round-robin dispatch)
    int idx = B >> 3;        // 0..95 within XCD
    int mt = X * 16 + idx / 6;
    int nt = idx - (idx / 6) * 6;
    int n0 = nt * GBN;
    int m0 = mt * GBM;
    int lrow = tid >> 1;
    int lk = (tid & 1) * 8;
    int ty = tid >> 4;   // 0..15 (m)
    int tx = tid & 15;   // 0..15 (n)

    const float* ap = A + (size_t)(m0 + lrow) * K + lk;
    const float* wpt = W + (size_t)(n0 + lrow) * K + lk;

    float acc[8][8];
    #pragma unroll
    for (int i = 0; i < 8; i++)
        #pragma unroll
        for (int j = 0; j < 8; j++) acc[i][j] = 0.f;

    // stage tile 0 into buffer 0
    float4 a0 = *(const float4*)(ap);
    float4 a1 = *(const float4*)(ap + 4);
    float4 w0 = *(const float4*)(wpt);
    float4 w1 = *(const float4*)(wpt + 4);
    {
        float* as = &As[0][lk][lrow];   // element j at +j*GBM
        as[0*GBM] = a0.x; as[1*GBM] = a0.y; as[2*GBM] = a0.z; as[3*GBM] = a0.w;
        as[4*GBM] = a1.x; as[5*GBM] = a1.y; as[6*GBM] = a1.z; as[7*GBM] = a1.w;
        float* wsp = &Ws[0][lk][lrow];
        wsp[0*GBN] = w0.x; wsp[1*GBN] = w0.y; wsp[2*GBN] = w0.z; wsp[3*GBN] = w0.w;
        wsp[4*GBN] = w1.x; wsp[5*GBN] = w1.y; wsp[6*GBN] = w1.z; wsp[7*GBN] = w1.w;
    }
    lds_barrier();

    int nk = K / GBK;
    int cur = 0;
    for (int it = 1; it < nk; it++) {
        // prefetch next tile to registers (hidden behind the 1024-FMA body)
        const float* apn = ap + it * GBK;
        const float* wpn = wpt + it * GBK;
        a0 = *(const float4*)(apn);
        a1 = *(const float4*)(apn + 4);
        w0 = *(const float4*)(wpn);
        w1 = *(const float4*)(wpn + 4);
        // compute current buffer
        #pragma unroll
        for (int k = 0; k < GBK; k++) {
            float4 va0 = *(const float4*)&As[cur][k][ty * 8];
            float4 va1 = *(const float4*)&As[cur][k][ty * 8 + 4];
            float4 vb0 = *(const float4*)&Ws[cur][k][tx * 4];
            float4 vb1 = *(const float4*)&Ws[cur][k][64 + tx * 4];
            float av[8] = {va0.x, va0.y, va0.z, va0.w, va1.x, va1.y, va1.z, va1.w};
            float bv[8] = {vb0.x, vb0.y, vb0.z, vb0.w, vb1.x, vb1.y, vb1.z, vb1.w};
            #pragma unroll
            for (int i = 0; i < 8; i++)
                #pragma unroll
                for (int j = 0; j < 8; j++)
                    acc[i][j] += av[i] * bv[j];
        }
        // write next buffer (no one reads it until the barrier)
        int nb = cur ^ 1;
        {
            float* as = &As[nb][lk][lrow];
            as[0*GBM] = a0.x; as[1*GBM] = a0.y; as[2*GBM] = a0.z; as[3*GBM] = a0.w;
            as[4*GBM] = a1.x; as[5*GBM] = a1.y; as[6*GBM] = a1.z; as[7*GBM] = a1.w;
            float* wsp = &Ws[nb][lk][lrow];
            wsp[0*GBN] = w0.x; wsp[1*GBN] = w0.y; wsp[2*GBN] = w0.z; wsp[3*GBN] = w0.w;
            wsp[4*GBN] = w1.x; wsp[5*GBN] = w1.y; wsp[6*GBN] = w1.z; wsp[7*GBN] = w1.w;
        }
        lds_barrier();
        cur = nb;
    }
    // final tile
    #pragma unroll
    for (int k = 0; k < GBK; k++) {
        float4 va0 = *(const float4*)&As[cur][k][ty * 8];
        float4 va1 = *(const float4*)&As[cur][k][ty * 8 + 4];
        float4 vb0 = *(const float4*)&Ws[cur][k][tx * 4];
        float4 vb1 = *(const float4*)&Ws[cur][k][64 + tx * 4];
        float av[8] = {va0.x, va0.y, va0.z, va0.w, va1.x, va1.y, va1.z, va1.w};
        float bv[8] = {vb0.x, vb0.y, vb0.z, vb0.w, vb1.x, vb1.y, vb1.z, vb1.w};
        #pragma unroll
        for (int i = 0; i < 8; i++)
            #pragma unroll
            for (int j = 0; j < 8; j++)
                acc[i][j] += av[i] * bv[j];
    }

    // store to xg layout: ((d*64+b)*256+t)*384 + g
    int c0 = n0 + tx * 4;
    int d = (c0 >= 384) ? 1 : 0;
    int g0 = c0 - d * 384;
    float4 bb0 = *(const float4*)(bias + c0);
    float4 bb1 = *(const float4*)(bias + c0 + 64);
    int mbase = m0 + ty * 8;
    #pragma unroll
    for (int i = 0; i < 8; i++) {
        int m = mbase + i;
        int b = m >> 8;
        int t = m & 255;
        float* op = out + (((size_t)(d * BATCH + b) * SEQ + t) * 384);
        float4 r0, r1;
        r0.x = acc[i][0] + bb0.x; r0.y = acc[i][1] + bb0.y;
        r0.z = acc[i][2] + bb0.z; r0.w = acc[i][3] + bb0.w;
        r1.x = acc[i][4] + bb1.x; r1.y = acc[i][5] + bb1.y;
        r1.z = acc[i][6] + bb1.z; r1.w = acc[i][7] + bb1.w;
        *(float4*)(op + g0) = r0;
        *(float4*)(op + g0 + 64) = r1;
    }
}

// ---------------- K4/K6: GRU recurrence, one wg per (dir, batch) ---------
// v4 = v3 (verified in round 4) + lds_barrier: thread (e2=i>>3, c=i&7)
// covers e in {e2, e2+64} with a 16-float k-chunk; 32 ds_read_b128/step;
// 8-lane combine = quad_sum (DPP) + ROW_HALF_MIRROR add, gray-code sel.
// The per-step barrier no longer drains vmcnt, so the xg prefetch (HBM)
// and the deferred out-store genuinely overlap the dot-product work —
// round-2/4 data showed per-step time pinned at ~1800cy regardless of LDS
// traffic, consistent with an HBM-latency drain at each __syncthreads.
__global__ __launch_bounds__(512, 2) void gru_rec_k(
    const float* __restrict__ xg,    // [2][64][256][384]
    const float* __restrict__ w_hh,  // [2][384][128]
    const float* __restrict__ b_hh,  // [2][384]
    const int*   __restrict__ lens,  // [64]
    float* __restrict__ out)         // [64][256][256], channel = d*128+j
{
    int d = blockIdx.x & 1;
    int b = blockIdx.x >> 1;
    int i = threadIdx.x;   // 0..511
    int c = i & 7;         // k-chunk: floats [16c, 16c+16)
    int e2 = i >> 3;       // 0..63
    int sel = (c ^ (c >> 1)) & 1;   // gray: invariant under c -> 7-c
    int eSel = e2 + 64 * sel;
    __shared__ __align__(16) float hS[2][HID];

    // rotated chunk order: slot j covers float4 index m = (j + (c>>1)) & 3
    int mj[4];
    #pragma unroll
    for (int j = 0; j < 4; j++) mj[j] = (j + (c >> 1)) & 3;

    const float* wb = w_hh + (size_t)d * 384 * HID;
    float4 wR0[4], wZ0[4], wN0[4], wR1[4], wZ1[4], wN1[4];
    #pragma unroll
    for (int j = 0; j < 4; j++) {
        int off = 16 * c + 4 * mj[j];
        wR0[j] = *(const float4*)(wb + (size_t)(e2)       * HID + off);
        wZ0[j] = *(const float4*)(wb + (size_t)(128 + e2) * HID + off);
        wN0[j] = *(const float4*)(wb + (size_t)(256 + e2) * HID + off);
        wR1[j] = *(const float4*)(wb + (size_t)(64 + e2)  * HID + off);
        wZ1[j] = *(const float4*)(wb + (size_t)(192 + e2) * HID + off);
        wN1[j] = *(const float4*)(wb + (size_t)(320 + e2) * HID + off);
    }
    float bhR = b_hh[d * 384 + eSel];
    float bhZ = b_hh[d * 384 + 128 + eSel];
    float bhN = b_hh[d * 384 + 256 + eSel];
    int len = lens[b];

    if (i < HID) hS[0][i] = 0.f;
    float hold = 0.f;
    lds_barrier();

    const float* xgb = xg + ((size_t)(d * BATCH + b)) * SEQ * 384;
    float* outb = out + (size_t)b * SEQ * 256 + d * HID;

    int t0 = d ? (SEQ - 1) : 0;
    float xvR = xgb[(size_t)t0 * 384 + eSel];
    float xvZ = xgb[(size_t)t0 * 384 + 128 + eSel];
    float xvN = xgb[(size_t)t0 * 384 + 256 + eSel];
    int tPrev = t0;

    // LDS float4 indices for the 4 rotated reads
    int idxA = c * 4 + mj[0];
    int idxB = c * 4 + mj[1];
    int idxC = c * 4 + mj[2];
    int idxD = c * 4 + mj[3];

    for (int s = 0; s < SEQ; s++) {
        int t = d ? (SEQ - 1 - s) : s;
        // deferred out-store of the previous step's h (stays in flight
        // across the raw barrier; no vmcnt drain)
        if (s && c < 2) outb[(size_t)tPrev * 256 + eSel] = hold;
        // prefetch next step's xg (consumed next iteration; HBM latency
        // overlaps this step's dot products + activations)
        int sn = (s + 1 < SEQ) ? (s + 1) : s;
        int tn = d ? (SEQ - 1 - sn) : sn;
        float nxvR = xgb[(size_t)tn * 384 + eSel];
        float nxvZ = xgb[(size_t)tn * 384 + 128 + eSel];
        float nxvN = xgb[(size_t)tn * 384 + 256 + eSel];

        const float4* hb = (const float4*)hS[s & 1];
        float4 hv0 = hb[idxA];
        float4 hv1 = hb[idxB];
        float4 hv2 = hb[idxC];
        float4 hv3 = hb[idxD];

        float sR0 = dot4(wR0[0], hv0) + dot4(wR0[1], hv1) + dot4(wR0[2], hv2) + dot4(wR0[3], hv3);
        float sZ0 = dot4(wZ0[0], hv0) + dot4(wZ0[1], hv1) + dot4(wZ0[2], hv2) + dot4(wZ0[3], hv3);
        float sN0 = dot4(wN0[0], hv0) + dot4(wN0[1], hv1) + dot4(wN0[2], hv2) + dot4(wN0[3], hv3);
        float sR1 = dot4(wR1[0], hv0) + dot4(wR1[1], hv1) + dot4(wR1[2], hv2) + dot4(wR1[3], hv3);
        float sZ1 = dot4(wZ1[0], hv0) + dot4(wZ1[1], hv1) + dot4(wZ1[2], hv2) + dot4(wZ1[3], hv3);
        float sN1 = dot4(wN1[0], hv0) + dot4(wN1[1], hv1) + dot4(wN1[2], hv2) + dot4(wN1[3], hv3);

        // quad partials (each quad covers one 64-float half of k)
        sR0 = quad_sum(sR0); sZ0 = quad_sum(sZ0); sN0 = quad_sum(sN0);
        sR1 = quad_sum(sR1); sZ1 = quad_sum(sZ1); sN1 = quad_sum(sN1);
        // select this lane's e, then add partner half (lane 7-c, same sel)
        float sR = mirror8_add(sel ? sR1 : sR0);
        float sZ = mirror8_add(sel ? sZ1 : sZ0);
        float sN = mirror8_add(sel ? sN1 : sN0);

        float r = sigm(xvR + sR + bhR);
        float z = sigm(xvZ + sZ + bhZ);
        float n = tanh_fast(xvN + r * (sN + bhN));
        float hnew = (1.f - z) * n + z * hold;
        hold = (t < len) ? hnew : hold;
        if (c < 2) hS[(s & 1) ^ 1][eSel] = hold;
        tPrev = t;
        xvR = nxvR; xvZ = nxvZ; xvN = nxvN;
        lds_barrier();
    }
    if (c < 2) outb[(size_t)tPrev * 256 + eSel] = hold;
}

// ---------------- K7: MLP (relu) + emissions -----------------------------
__global__ __launch_bounds__(128) void mlp_emis_k(
    const float* __restrict__ h1,    // [16384][256]
    const float* __restrict__ w1,    // [256][128]
    const float* __restrict__ b1,    // [128]
    const float* __restrict__ w2,    // [128][17]
    const float* __restrict__ b2,    // [17]
    float* __restrict__ emis)        // [16384][17]
{
    __shared__ __align__(16) float hrow[8 * 256];
    __shared__ float hid[8][HID];
    int p0 = blockIdx.x * 8;
    int tid = threadIdx.x;
    for (int e = tid; e < 8 * 256; e += 128)
        hrow[e] = h1[(size_t)p0 * 256 + e];
    __syncthreads();
    float acc[8];
    float bb = b1[tid];
    #pragma unroll
    for (int i = 0; i < 8; i++) acc[i] = bb;
    for (int k = 0; k < 256; k++) {
        float wv = w1[k * HID + tid];
        #pragma unroll
        for (int i = 0; i < 8; i++) acc[i] += hrow[i * 256 + k] * wv;
    }
    #pragma unroll
    for (int i = 0; i < 8; i++) hid[i][tid] = fmaxf(acc[i], 0.f);
    __syncthreads();
    for (int idx = tid; idx < 8 * NT; idx += 128) {
        int pos = idx / NT;
        int tg = idx - pos * NT;
        float a = b2[tg];
        for (int k = 0; k < HID; k++) a += hid[pos][k] * w2[k * NT + tg];
        emis[(size_t)(p0 + pos) * NT + tg] = a;
    }
}

// ---------------- K8: CRF score + forward algorithm ----------------------
__global__ __launch_bounds__(64) void crf_k(
    const float* __restrict__ emis,   // [64][256][17]
    const float* __restrict__ start,
    const float* __restrict__ endv,
    const float* __restrict__ trans,  // [17][17]
    const int*   __restrict__ target, // [64][256]
    const int*   __restrict__ lens,
    float* __restrict__ llh)          // [64]
{
    int b = blockIdx.x;
    int tid = threadIdx.x;
    __shared__ float tr[NT * NT];
    __shared__ float aSh[NT];
    __shared__ float scoreSh;
    for (int e = tid; e < NT * NT; e += 64) tr[e] = trans[e];
    __syncthreads();
    int len = lens[b];
    const int* tgt = target + b * SEQ;
    const float* eb = emis + (size_t)b * SEQ * NT;

    // gold score (parallel over t, reduce in-wave)
    float part = 0.f;
    for (int t = 1 + tid; t < SEQ; t += 64) {
        if (t < len) {
            int tp = tgt[t - 1], tc = tgt[t];
            part += tr[tp * NT + tc] + eb[(size_t)t * NT + tc];
        }
    }
    #pragma unroll
    for (int off = 32; off > 0; off >>= 1)
        part += __shfl_down(part, off, 64);
    if (tid == 0) {
        int t0 = tgt[0];
        scoreSh = part + start[t0] + eb[t0] + endv[tgt[len - 1]];
    }

    // forward algorithm
    float a = (tid < NT) ? (start[tid] + eb[tid]) : 0.f;
    for (int t = 1; t < SEQ; t++) {
        if (tid < NT) aSh[tid] = a;
        __syncthreads();
        if (t < len && tid < NT) {
            float m = -1e30f;
            #pragma unroll
            for (int i = 0; i < NT; i++)
                m = fmaxf(m, aSh[i] + tr[i * NT + tid]);
            float ssum = 0.f;
            #pragma unroll
            for (int i = 0; i < NT; i++)
                ssum += __expf(aSh[i] + tr[i * NT + tid] - m);
            a = m + __logf(ssum) + eb[(size_t)t * NT + tid];
        }
        __syncthreads();
    }
    float v = (tid < NT) ? (a + endv[tid]) : -1e30f;
    float m = v;
    #pragma unroll
    for (int off = 32; off > 0; off >>= 1)
        m = fmaxf(m, __shfl_down(m, off, 64));
    m = __shfl(m, 0, 64);
    float e = (tid < NT) ? __expf(v - m) : 0.f;
    #pragma unroll
    for (int off = 32; off > 0; off >>= 1)
        e += __shfl_down(e, off, 64);
    if (tid == 0) {
        float logz = m + __logf(e);
        llh[b] = scoreSh - logz;
    }
}

// ---------------- K9: final loss -----------------------------------------
__global__ __launch_bounds__(64) void finalize_k(
    const float* __restrict__ llh,
    const int*   __restrict__ lens,
    float* __restrict__ out)
{
    int tid = threadIdx.x;
    float s = llh[tid];
    float lf = (float)lens[tid];
    #pragma unroll
    for (int off = 32; off > 0; off >>= 1) {
        s += __shfl_down(s, off, 64);
        lf += __shfl_down(lf, off, 64);
    }
    if (tid == 0) out[0] = -(s / lf);
}

extern "C" void kernel_launch(void* const* d_in, const int* in_sizes, int n_in,
                              void* d_out, int out_size, void* d_ws, size_t ws_size,
                              hipStream_t stream) {
    const float* char_emb = (const float*)d_in[0];
    const float* conv_w   = (const float*)d_in[1];
    const float* conv_b   = (const float*)d_in[2];
    const float* word_emb = (const float*)d_in[3];
    const float* w_ih_l0  = (const float*)d_in[4];
    const float* w_hh_l0  = (const float*)d_in[5];
    const float* b_ih_l0  = (const float*)d_in[6];
    const float* b_hh_l0  = (const float*)d_in[7];
    const float* w_ih_l1  = (const float*)d_in[8];
    const float* w_hh_l1  = (const float*)d_in[9];
    const float* b_ih_l1  = (const float*)d_in[10];
    const float* b_hh_l1  = (const float*)d_in[11];
    const float* mlp_w1   = (const float*)d_in[12];
    const float* mlp_b1   = (const float*)d_in[13];
    const float* mlp_w2   = (const float*)d_in[14];
    const float* mlp_b2   = (const float*)d_in[15];
    const float* crf_start= (const float*)d_in[16];
    const float* crf_end  = (const float*)d_in[17];
    const float* crf_trans= (const float*)d_in[18];
    const int* bcw   = (const int*)d_in[19];
    // d_in[20] batched_char_words_len: unused by reference
    const int* bcwi  = (const int*)d_in[21];
    const int* btok  = (const int*)d_in[22];
    const int* blen  = (const int*)d_in[23];
    const int* target= (const int*)d_in[24];

    float* ws    = (float*)d_ws;
    float* xg    = ws + OFF_XG;
    float* texts = ws + OFF_TEXTS;   // aliased: h0 overwrites texts after xg0 GEMM
    float* h0    = texts;
    float* h1    = ws + OFF_H1;
    float* tok   = ws + OFF_TOK;
    float* emis  = ws + OFF_EMIS;
    float* wpad  = ws + OFF_WPAD;
    float* llh   = ws + OFF_LLH;

    hipMemsetAsync(tok, 0, CDIM * sizeof(float), stream);  // tok_enc row 0 = zeros
    pad_w_k<<<768, 64, 0, stream>>>(w_ih_l0, wpad);
    char_conv_k<<<NW / 8, 256, 0, stream>>>(char_emb, conv_w, conv_b, bcw, tok);
    build_texts_k<<<NPOS, 128, 0, stream>>>(word_emb, tok, btok, bcwi, texts);
    gemm_xg_k<<<dim3(768 / GBN, NPOS / GBM), 256, 0, stream>>>(texts, wpad, b_ih_l0, xg, IN0P);
    gru_rec_k<<<2 * BATCH, 512, 0, stream>>>(xg, w_hh_l0, b_hh_l0, blen, h0);
    gemm_xg_k<<<dim3(768 / GBN, NPOS / GBM), 256, 0, stream>>>(h0, w_ih_l1, b_ih_l1, xg, IN1);
    gru_rec_k<<<2 * BATCH, 512, 0, stream>>>(xg, w_hh_l1, b_hh_l1, blen, h1);
    mlp_emis_k<<<NPOS / 8, 128, 0, stream>>>(h1, mlp_w1, mlp_b1, mlp_w2, mlp_b2, emis);
    crf_k<<<BATCH, 64, 0, stream>>>(emis, crf_start, crf_end, crf_trans, target, blen, llh);
    finalize_k<<<1, 64, 0, stream>>>(llh, blen, (float*)d_out);
}

// Round 6
// 915.503 us; speedup vs baseline: 1.3600x; 1.0113x over previous
//
#include <hip/hip_runtime.h>
#include <cstddef>

// Problem dims
#define BATCH 64
#define SEQ   256
#define VOCAB 50000
#define DIM   300
#define NW    8192
#define CLEN  16
#define CDIM  30
#define CHC   30
#define HID   128
#define NT    17
#define IN0   (DIM + CHC)   // 330
#define IN0P  336           // padded to multiple of 16
#define IN1   (2 * HID)     // 256
#define NPOS  (BATCH * SEQ) // 16384

// Workspace layout (floats)
constexpr size_t SZ_XG    = 2ull * BATCH * SEQ * 384;    // 12,582,912
constexpr size_t SZ_TEXTS = (size_t)NPOS * IN0P;         // 5,505,024 (aliased as h0 after GEMM0)
constexpr size_t SZ_H1    = (size_t)NPOS * 256;          // 4,194,304
constexpr size_t SZ_TOK   = 245792;                      // (NW+1)*30 rounded
constexpr size_t SZ_EMIS  = (size_t)NPOS * NT;           // 278,528
constexpr size_t SZ_WPAD  = 768ull * IN0P;               // 258,048
constexpr size_t OFF_XG    = 0;
constexpr size_t OFF_TEXTS = OFF_XG + SZ_XG;
constexpr size_t OFF_H1    = OFF_TEXTS + SZ_TEXTS;
constexpr size_t OFF_TOK   = OFF_H1 + SZ_H1;
constexpr size_t OFF_EMIS  = OFF_TOK + SZ_TOK;
constexpr size_t OFF_WPAD  = OFF_EMIS + SZ_EMIS;
constexpr size_t OFF_LLH   = OFF_WPAD + SZ_WPAD;

__device__ __forceinline__ float sigm(float x) {
    return 1.f / (1.f + __expf(-x));
}
__device__ __forceinline__ float tanh_fast(float x) {
    x = fminf(fmaxf(x, -15.f), 15.f);
    float e = __expf(-2.f * x);
    return (1.f - e) / (1.f + e);
}
__device__ __forceinline__ float dot4(float4 a, float4 b) {
    return a.x * b.x + a.y * b.y + a.z * b.z + a.w * b.w;
}
// Raw LDS-only barrier: __syncthreads() drains vmcnt at every barrier;
// inter-wave data here flows only through LDS, so lgkmcnt(0) suffices and
// global loads/stores stay in flight across the barrier.
__device__ __forceinline__ void lds_barrier() {
    asm volatile("s_waitcnt lgkmcnt(0)\n\ts_barrier" ::: "memory");
}
// Sum across the 4 lanes of a quad using DPP quad_perm (VALU-only).
__device__ __forceinline__ float quad_sum(float x) {
    int y = __builtin_amdgcn_update_dpp(0, __float_as_int(x), 0xB1, 0xF, 0xF, false); // [1,0,3,2]
    x += __int_as_float(y);
    y = __builtin_amdgcn_update_dpp(0, __float_as_int(x), 0x4E, 0xF, 0xF, false);     // [2,3,0,1]
    x += __int_as_float(y);
    return x;
}
// add partner lane (7 - (lane&7))'s value via DPP ROW_HALF_MIRROR (0x141).
__device__ __forceinline__ float mirror8_add(float x) {
    int y = __builtin_amdgcn_update_dpp(0, __float_as_int(x), 0x141, 0xF, 0xF, false);
    return x + __int_as_float(y);
}

// ---------------- K1: char CNN + relu + maxpool -> tok_enc[(n+1)][30] ----
__global__ __launch_bounds__(256) void char_conv_k(
    const float* __restrict__ char_emb,  // [500][30]
    const float* __restrict__ conv_w,    // [30][30][3]
    const float* __restrict__ conv_b,    // [30]
    const int*   __restrict__ words,     // [8192][16]
    float* __restrict__ tok_enc)         // [8193][30]
{
    __shared__ __align__(16) float cs[8][CLEN][CDIM];
    __shared__ float wsm[CHC * CDIM * 3];
    __shared__ float bs[CHC];
    int n0 = blockIdx.x * 8;
    int tid = threadIdx.x;
    for (int e = tid; e < CHC * CDIM * 3; e += 256) wsm[e] = conv_w[e];
    if (tid < CHC) bs[tid] = conv_b[tid];
    for (int e = tid; e < 8 * CLEN * CDIM; e += 256) {
        int wi = e / (CLEN * CDIM);
        int rem = e - wi * (CLEN * CDIM);
        int l = rem / CDIM;
        int i = rem - l * CDIM;
        int ci = words[(n0 + wi) * CLEN + l];
        cs[wi][l][i] = char_emb[ci * CDIM + i];
    }
    __syncthreads();
    int wi = tid >> 5;
    int o = tid & 31;
    if (o < CHC) {
        float best = -1e30f;
        for (int l = 0; l < CLEN; l++) {
            float s = 0.f;
            #pragma unroll
            for (int k = 0; k < 3; k++) {
                int ll = l + k - 1;
                if (ll >= 0 && ll < CLEN) {
                    #pragma unroll
                    for (int i = 0; i < CDIM; i++)
                        s += cs[wi][ll][i] * wsm[(o * CDIM + i) * 3 + k];
                }
            }
            best = fmaxf(best, s);
        }
        tok_enc[(size_t)(n0 + wi + 1) * CDIM + o] = fmaxf(best + bs[o], 0.f);
    }
}

// ---------------- K2: texts = concat(word_emb[tok], tok_enc[widx]), pad to 336
__global__ __launch_bounds__(128) void build_texts_k(
    const float* __restrict__ word_emb,
    const float* __restrict__ tok_enc,
    const int*   __restrict__ tokens,
    const int*   __restrict__ widx,
    float* __restrict__ texts)
{
    int p = blockIdx.x;
    int tok = tokens[p];
    int ci = widx[p];
    float* o = texts + (size_t)p * IN0P;
    const float* wr = word_emb + (size_t)tok * DIM;
    const float* tr = tok_enc + (size_t)ci * CDIM;
    for (int c = threadIdx.x; c < IN0P; c += 128)
        o[c] = (c < DIM) ? wr[c] : (c < IN0 ? tr[c - DIM] : 0.f);
}

// ---------------- K2b: pad w_ih_l0 (768x330) -> (768x336) ---------------
__global__ __launch_bounds__(64) void pad_w_k(
    const float* __restrict__ w, float* __restrict__ wp)
{
    int r = blockIdx.x;
    for (int c = threadIdx.x; c < IN0P; c += 64)
        wp[(size_t)r * IN0P + c] = (c < IN0) ? w[(size_t)r * IN0 + c] : 0.f;
}

// ---------------- K3/K5: xg = A @ W_ih^T + b_ih, stored [d][b][t][g] -----
// A: [16384][K] row-major (K multiple of 16), W: [768][K] row-major
// LDS double-buffered A and W, 1 lds_barrier per k-tile, register prefetch,
// conflict-free B fragments (tx*4 / 64+tx*4), XCD-bijective swizzle.
#define GBM 128
#define GBN 128
#define GBK 16
__global__ __launch_bounds__(256, 3) void gemm_xg_k(
    const float* __restrict__ A,
    const float* __restrict__ W,
    const float* __restrict__ bias,
    float* __restrict__ out,
    int K)
{
    __shared__ __align__(16) float As[2][GBK][GBM];
    __shared__ __align__(16) float Ws[2][GBK][GBN];
    int tid = threadIdx.x;
    int B = blockIdx.y * gridDim.x + blockIdx.x;   // 0..767, gridDim.x = 6
    int X = B & 7;           // XCD (round-robin dispatch)
    int idx = B >> 3;        // 0..95 within XCD
    int mt = X * 16 + idx / 6;
    int nt = idx - (idx / 6) * 6;
    int n0 = nt * GBN;
    int m0 = mt * GBM;
    int lrow = tid >> 1;
    int lk = (tid & 1) * 8;
    int ty = tid >> 4;   // 0..15 (m)
    int tx = tid & 15;   // 0..15 (n)

    const float* ap = A + (size_t)(m0 + lrow) * K + lk;
    const float* wpt = W + (size_t)(n0 + lrow) * K + lk;

    float acc[8][8];
    #pragma unroll
    for (int i = 0; i < 8; i++)
        #pragma unroll
        for (int j = 0; j < 8; j++) acc[i][j] = 0.f;

    // stage tile 0 into buffer 0
    float4 a0 = *(const float4*)(ap);
    float4 a1 = *(const float4*)(ap + 4);
    float4 w0 = *(const float4*)(wpt);
    float4 w1 = *(const float4*)(wpt + 4);
    {
        float* as = &As[0][lk][lrow];   // element j at +j*GBM
        as[0*GBM] = a0.x; as[1*GBM] = a0.y; as[2*GBM] = a0.z; as[3*GBM] = a0.w;
        as[4*GBM] = a1.x; as[5*GBM] = a1.y; as[6*GBM] = a1.z; as[7*GBM] = a1.w;
        float* wsp = &Ws[0][lk][lrow];
        wsp[0*GBN] = w0.x; wsp[1*GBN] = w0.y; wsp[2*GBN] = w0.z; wsp[3*GBN] = w0.w;
        wsp[4*GBN] = w1.x; wsp[5*GBN] = w1.y; wsp[6*GBN] = w1.z; wsp[7*GBN] = w1.w;
    }
    lds_barrier();

    int nk = K / GBK;
    int cur = 0;
    for (int it = 1; it < nk; it++) {
        // prefetch next tile to registers (hidden behind the 1024-FMA body)
        const float* apn = ap + it * GBK;
        const float* wpn = wpt + it * GBK;
        a0 = *(const float4*)(apn);
        a1 = *(const float4*)(apn + 4);
        w0 = *(const float4*)(wpn);
        w1 = *(const float4*)(wpn + 4);
        // compute current buffer
        #pragma unroll
        for (int k = 0; k < GBK; k++) {
            float4 va0 = *(const float4*)&As[cur][k][ty * 8];
            float4 va1 = *(const float4*)&As[cur][k][ty * 8 + 4];
            float4 vb0 = *(const float4*)&Ws[cur][k][tx * 4];
            float4 vb1 = *(const float4*)&Ws[cur][k][64 + tx * 4];
            float av[8] = {va0.x, va0.y, va0.z, va0.w, va1.x, va1.y, va1.z, va1.w};
            float bv[8] = {vb0.x, vb0.y, vb0.z, vb0.w, vb1.x, vb1.y, vb1.z, vb1.w};
            #pragma unroll
            for (int i = 0; i < 8; i++)
                #pragma unroll
                for (int j = 0; j < 8; j++)
                    acc[i][j] += av[i] * bv[j];
        }
        // write next buffer (no one reads it until the barrier)
        int nb = cur ^ 1;
        {
            float* as = &As[nb][lk][lrow];
            as[0*GBM] = a0.x; as[1*GBM] = a0.y; as[2*GBM] = a0.z; as[3*GBM] = a0.w;
            as[4*GBM] = a1.x; as[5*GBM] = a1.y; as[6*GBM] = a1.z; as[7*GBM] = a1.w;
            float* wsp = &Ws[nb][lk][lrow];
            wsp[0*GBN] = w0.x; wsp[1*GBN] = w0.y; wsp[2*GBN] = w0.z; wsp[3*GBN] = w0.w;
            wsp[4*GBN] = w1.x; wsp[5*GBN] = w1.y; wsp[6*GBN] = w1.z; wsp[7*GBN] = w1.w;
        }
        lds_barrier();
        cur = nb;
    }
    // final tile
    #pragma unroll
    for (int k = 0; k < GBK; k++) {
        float4 va0 = *(const float4*)&As[cur][k][ty * 8];
        float4 va1 = *(const float4*)&As[cur][k][ty * 8 + 4];
        float4 vb0 = *(const float4*)&Ws[cur][k][tx * 4];
        float4 vb1 = *(const float4*)&Ws[cur][k][64 + tx * 4];
        float av[8] = {va0.x, va0.y, va0.z, va0.w, va1.x, va1.y, va1.z, va1.w};
        float bv[8] = {vb0.x, vb0.y, vb0.z, vb0.w, vb1.x, vb1.y, vb1.z, vb1.w};
        #pragma unroll
        for (int i = 0; i < 8; i++)
            #pragma unroll
            for (int j = 0; j < 8; j++)
                acc[i][j] += av[i] * bv[j];
    }

    // store to xg layout: ((d*64+b)*256+t)*384 + g
    int c0 = n0 + tx * 4;
    int d = (c0 >= 384) ? 1 : 0;
    int g0 = c0 - d * 384;
    float4 bb0 = *(const float4*)(bias + c0);
    float4 bb1 = *(const float4*)(bias + c0 + 64);
    int mbase = m0 + ty * 8;
    #pragma unroll
    for (int i = 0; i < 8; i++) {
        int m = mbase + i;
        int b = m >> 8;
        int t = m & 255;
        float* op = out + (((size_t)(d * BATCH + b) * SEQ + t) * 384);
        float4 r0, r1;
        r0.x = acc[i][0] + bb0.x; r0.y = acc[i][1] + bb0.y;
        r0.z = acc[i][2] + bb0.z; r0.w = acc[i][3] + bb0.w;
        r1.x = acc[i][4] + bb1.x; r1.y = acc[i][5] + bb1.y;
        r1.z = acc[i][6] + bb1.z; r1.w = acc[i][7] + bb1.w;
        *(float4*)(op + g0) = r0;
        *(float4*)(op + g0 + 64) = r1;
    }
}

// ---------------- K4/K6: GRU recurrence, one wg per (dir, batch) ---------
// v5: the round-0..5 invariance (~192us across 4 structural variants) was
// L2-BW on WEIGHT RELOADS: VGPR_Count=72 proves the 24 float4 weight arrays
// were never register-resident (96 VGPRs min); each step re-read 196 KB of
// W_hh per wg from L2 -> per-XCD 16 wgs x 196 KB / 1.8 KB/cy = ~1750cy/step
// = the measured 1800. Fix: 24 INDIVIDUALLY-NAMED float4 registers (no
// array indexing anywhere in their lifetime, rule #20) so the weights are
// truly loaded once. Expect VGPR ~150, step -> VALU/LDS-bound.
__global__ __launch_bounds__(512, 2) void gru_rec_k(
    const float* __restrict__ xg,    // [2][64][256][384]
    const float* __restrict__ w_hh,  // [2][384][128]
    const float* __restrict__ b_hh,  // [2][384]
    const int*   __restrict__ lens,  // [64]
    float* __restrict__ out)         // [64][256][256], channel = d*128+j
{
    int d = blockIdx.x & 1;
    int b = blockIdx.x >> 1;
    int i = threadIdx.x;   // 0..511
    int c = i & 7;         // k-chunk: floats [16c, 16c+16)
    int e2 = i >> 3;       // 0..63
    int sel = (c ^ (c >> 1)) & 1;   // gray: invariant under c -> 7-c
    int eSel = e2 + 64 * sel;
    __shared__ __align__(16) float hS[2][HID];

    // rotated chunk order: read j covers float4 index m = (j + (c>>1)) & 3
    int rot = c >> 1;
    int mj0 = (0 + rot) & 3;
    int mj1 = (1 + rot) & 3;
    int mj2 = (2 + rot) & 3;
    int mj3 = (3 + rot) & 3;
    int off0 = 16 * c + 4 * mj0;
    int off1 = 16 * c + 4 * mj1;
    int off2 = 16 * c + 4 * mj2;
    int off3 = 16 * c + 4 * mj3;

    const float* wb = w_hh + (size_t)d * 384 * HID;
    const float* pR0 = wb + (size_t)(e2)       * HID;
    const float* pZ0 = wb + (size_t)(128 + e2) * HID;
    const float* pN0 = wb + (size_t)(256 + e2) * HID;
    const float* pR1 = wb + (size_t)(64 + e2)  * HID;
    const float* pZ1 = wb + (size_t)(192 + e2) * HID;
    const float* pN1 = wb + (size_t)(320 + e2) * HID;
    // 24 named float4 weight registers (96 VGPRs) — loaded ONCE.
    float4 wR0a = *(const float4*)(pR0 + off0);
    float4 wR0b = *(const float4*)(pR0 + off1);
    float4 wR0c = *(const float4*)(pR0 + off2);
    float4 wR0d = *(const float4*)(pR0 + off3);
    float4 wZ0a = *(const float4*)(pZ0 + off0);
    float4 wZ0b = *(const float4*)(pZ0 + off1);
    float4 wZ0c = *(const float4*)(pZ0 + off2);
    float4 wZ0d = *(const float4*)(pZ0 + off3);
    float4 wN0a = *(const float4*)(pN0 + off0);
    float4 wN0b = *(const float4*)(pN0 + off1);
    float4 wN0c = *(const float4*)(pN0 + off2);
    float4 wN0d = *(const float4*)(pN0 + off3);
    float4 wR1a = *(const float4*)(pR1 + off0);
    float4 wR1b = *(const float4*)(pR1 + off1);
    float4 wR1c = *(const float4*)(pR1 + off2);
    float4 wR1d = *(const float4*)(pR1 + off3);
    float4 wZ1a = *(const float4*)(pZ1 + off0);
    float4 wZ1b = *(const float4*)(pZ1 + off1);
    float4 wZ1c = *(const float4*)(pZ1 + off2);
    float4 wZ1d = *(const float4*)(pZ1 + off3);
    float4 wN1a = *(const float4*)(pN1 + off0);
    float4 wN1b = *(const float4*)(pN1 + off1);
    float4 wN1c = *(const float4*)(pN1 + off2);
    float4 wN1d = *(const float4*)(pN1 + off3);

    float bhR = b_hh[d * 384 + eSel];
    float bhZ = b_hh[d * 384 + 128 + eSel];
    float bhN = b_hh[d * 384 + 256 + eSel];
    int len = lens[b];

    if (i < HID) hS[0][i] = 0.f;
    float hold = 0.f;
    lds_barrier();

    const float* xgb = xg + ((size_t)(d * BATCH + b)) * SEQ * 384;
    float* outb = out + (size_t)b * SEQ * 256 + d * HID;

    int t0 = d ? (SEQ - 1) : 0;
    float xvR = xgb[(size_t)t0 * 384 + eSel];
    float xvZ = xgb[(size_t)t0 * 384 + 128 + eSel];
    float xvN = xgb[(size_t)t0 * 384 + 256 + eSel];
    int tPrev = t0;

    // LDS float4 indices for the 4 rotated reads
    int idxA = c * 4 + mj0;
    int idxB = c * 4 + mj1;
    int idxC = c * 4 + mj2;
    int idxD = c * 4 + mj3;

    for (int s = 0; s < SEQ; s++) {
        int t = d ? (SEQ - 1 - s) : s;
        // deferred out-store of the previous step's h (in flight across the
        // raw barrier; no vmcnt drain)
        if (s && c < 2) outb[(size_t)tPrev * 256 + eSel] = hold;
        // prefetch next step's xg
        int sn = (s + 1 < SEQ) ? (s + 1) : s;
        int tn = d ? (SEQ - 1 - sn) : sn;
        float nxvR = xgb[(size_t)tn * 384 + eSel];
        float nxvZ = xgb[(size_t)tn * 384 + 128 + eSel];
        float nxvN = xgb[(size_t)tn * 384 + 256 + eSel];

        const float4* hb = (const float4*)hS[s & 1];
        float4 hv0 = hb[idxA];
        float4 hv1 = hb[idxB];
        float4 hv2 = hb[idxC];
        float4 hv3 = hb[idxD];

        float sR0 = dot4(wR0a, hv0) + dot4(wR0b, hv1) + dot4(wR0c, hv2) + dot4(wR0d, hv3);
        float sZ0 = dot4(wZ0a, hv0) + dot4(wZ0b, hv1) + dot4(wZ0c, hv2) + dot4(wZ0d, hv3);
        float sN0 = dot4(wN0a, hv0) + dot4(wN0b, hv1) + dot4(wN0c, hv2) + dot4(wN0d, hv3);
        float sR1 = dot4(wR1a, hv0) + dot4(wR1b, hv1) + dot4(wR1c, hv2) + dot4(wR1d, hv3);
        float sZ1 = dot4(wZ1a, hv0) + dot4(wZ1b, hv1) + dot4(wZ1c, hv2) + dot4(wZ1d, hv3);
        float sN1 = dot4(wN1a, hv0) + dot4(wN1b, hv1) + dot4(wN1c, hv2) + dot4(wN1d, hv3);

        // quad partials (each quad covers one 64-float half of k)
        sR0 = quad_sum(sR0); sZ0 = quad_sum(sZ0); sN0 = quad_sum(sN0);
        sR1 = quad_sum(sR1); sZ1 = quad_sum(sZ1); sN1 = quad_sum(sN1);
        // select this lane's e, then add partner half (lane 7-c, same sel)
        float sR = mirror8_add(sel ? sR1 : sR0);
        float sZ = mirror8_add(sel ? sZ1 : sZ0);
        float sN = mirror8_add(sel ? sN1 : sN0);

        float r = sigm(xvR + sR + bhR);
        float z = sigm(xvZ + sZ + bhZ);
        float n = tanh_fast(xvN + r * (sN + bhN));
        float hnew = (1.f - z) * n + z * hold;
        hold = (t < len) ? hnew : hold;
        if (c < 2) hS[(s & 1) ^ 1][eSel] = hold;
        tPrev = t;
        xvR = nxvR; xvZ = nxvZ; xvN = nxvN;
        lds_barrier();
    }
    if (c < 2) outb[(size_t)tPrev * 256 + eSel] = hold;
}

// ---------------- K7: MLP (relu) + emissions -----------------------------
__global__ __launch_bounds__(128) void mlp_emis_k(
    const float* __restrict__ h1,    // [16384][256]
    const float* __restrict__ w1,    // [256][128]
    const float* __restrict__ b1,    // [128]
    const float* __restrict__ w2,    // [128][17]
    const float* __restrict__ b2,    // [17]
    float* __restrict__ emis)        // [16384][17]
{
    __shared__ __align__(16) float hrow[8 * 256];
    __shared__ float hid[8][HID];
    int p0 = blockIdx.x * 8;
    int tid = threadIdx.x;
    for (int e = tid; e < 8 * 256; e += 128)
        hrow[e] = h1[(size_t)p0 * 256 + e];
    __syncthreads();
    float acc[8];
    float bb = b1[tid];
    #pragma unroll
    for (int i = 0; i < 8; i++) acc[i] = bb;
    for (int k = 0; k < 256; k++) {
        float wv = w1[k * HID + tid];
        #pragma unroll
        for (int i = 0; i < 8; i++) acc[i] += hrow[i * 256 + k] * wv;
    }
    #pragma unroll
    for (int i = 0; i < 8; i++) hid[i][tid] = fmaxf(acc[i], 0.f);
    __syncthreads();
    for (int idx = tid; idx < 8 * NT; idx += 128) {
        int pos = idx / NT;
        int tg = idx - pos * NT;
        float a = b2[tg];
        for (int k = 0; k < HID; k++) a += hid[pos][k] * w2[k * NT + tg];
        emis[(size_t)(p0 + pos) * NT + tg] = a;
    }
}

// ---------------- K8: CRF score + forward algorithm ----------------------
__global__ __launch_bounds__(64) void crf_k(
    const float* __restrict__ emis,   // [64][256][17]
    const float* __restrict__ start,
    const float* __restrict__ endv,
    const float* __restrict__ trans,  // [17][17]
    const int*   __restrict__ target, // [64][256]
    const int*   __restrict__ lens,
    float* __restrict__ llh)          // [64]
{
    int b = blockIdx.x;
    int tid = threadIdx.x;
    __shared__ float tr[NT * NT];
    __shared__ float aSh[NT];
    __shared__ float scoreSh;
    for (int e = tid; e < NT * NT; e += 64) tr[e] = trans[e];
    __syncthreads();
    int len = lens[b];
    const int* tgt = target + b * SEQ;
    const float* eb = emis + (size_t)b * SEQ * NT;

    // gold score (parallel over t, reduce in-wave)
    float part = 0.f;
    for (int t = 1 + tid; t < SEQ; t += 64) {
        if (t < len) {
            int tp = tgt[t - 1], tc = tgt[t];
            part += tr[tp * NT + tc] + eb[(size_t)t * NT + tc];
        }
    }
    #pragma unroll
    for (int off = 32; off > 0; off >>= 1)
        part += __shfl_down(part, off, 64);
    if (tid == 0) {
        int t0 = tgt[0];
        scoreSh = part + start[t0] + eb[t0] + endv[tgt[len - 1]];
    }

    // forward algorithm
    float a = (tid < NT) ? (start[tid] + eb[tid]) : 0.f;
    for (int t = 1; t < SEQ; t++) {
        if (tid < NT) aSh[tid] = a;
        __syncthreads();
        if (t < len && tid < NT) {
            float m = -1e30f;
            #pragma unroll
            for (int i = 0; i < NT; i++)
                m = fmaxf(m, aSh[i] + tr[i * NT + tid]);
            float ssum = 0.f;
            #pragma unroll
            for (int i = 0; i < NT; i++)
                ssum += __expf(aSh[i] + tr[i * NT + tid] - m);
            a = m + __logf(ssum) + eb[(size_t)t * NT + tid];
        }
        __syncthreads();
    }
    float v = (tid < NT) ? (a + endv[tid]) : -1e30f;
    float m = v;
    #pragma unroll
    for (int off = 32; off > 0; off >>= 1)
        m = fmaxf(m, __shfl_down(m, off, 64));
    m = __shfl(m, 0, 64);
    float e = (tid < NT) ? __expf(v - m) : 0.f;
    #pragma unroll
    for (int off = 32; off > 0; off >>= 1)
        e += __shfl_down(e, off, 64);
    if (tid == 0) {
        float logz = m + __logf(e);
        llh[b] = scoreSh - logz;
    }
}

// ---------------- K9: final loss -----------------------------------------
__global__ __launch_bounds__(64) void finalize_k(
    const float* __restrict__ llh,
    const int*   __restrict__ lens,
    float* __restrict__ out)
{
    int tid = threadIdx.x;
    float s = llh[tid];
    float lf = (float)lens[tid];
    #pragma unroll
    for (int off = 32; off > 0; off >>= 1) {
        s += __shfl_down(s, off, 64);
        lf += __shfl_down(lf, off, 64);
    }
    if (tid == 0) out[0] = -(s / lf);
}

extern "C" void kernel_launch(void* const* d_in, const int* in_sizes, int n_in,
                              void* d_out, int out_size, void* d_ws, size_t ws_size,
                              hipStream_t stream) {
    const float* char_emb = (const float*)d_in[0];
    const float* conv_w   = (const float*)d_in[1];
    const float* conv_b   = (const float*)d_in[2];
    const float* word_emb = (const float*)d_in[3];
    const float* w_ih_l0  = (const float*)d_in[4];
    const float* w_hh_l0  = (const float*)d_in[5];
    const float* b_ih_l0  = (const float*)d_in[6];
    const float* b_hh_l0  = (const float*)d_in[7];
    const float* w_ih_l1  = (const float*)d_in[8];
    const float* w_hh_l1  = (const float*)d_in[9];
    const float* b_ih_l1  = (const float*)d_in[10];
    const float* b_hh_l1  = (const float*)d_in[11];
    const float* mlp_w1   = (const float*)d_in[12];
    const float* mlp_b1   = (const float*)d_in[13];
    const float* mlp_w2   = (const float*)d_in[14];
    const float* mlp_b2   = (const float*)d_in[15];
    const float* crf_start= (const float*)d_in[16];
    const float* crf_end  = (const float*)d_in[17];
    const float* crf_trans= (const float*)d_in[18];
    const int* bcw   = (const int*)d_in[19];
    // d_in[20] batched_char_words_len: unused by reference
    const int* bcwi  = (const int*)d_in[21];
    const int* btok  = (const int*)d_in[22];
    const int* blen  = (const int*)d_in[23];
    const int* target= (const int*)d_in[24];

    float* ws    = (float*)d_ws;
    float* xg    = ws + OFF_XG;
    float* texts = ws + OFF_TEXTS;   // aliased: h0 overwrites texts after xg0 GEMM
    float* h0    = texts;
    float* h1    = ws + OFF_H1;
    float* tok   = ws + OFF_TOK;
    float* emis  = ws + OFF_EMIS;
    float* wpad  = ws + OFF_WPAD;
    float* llh   = ws + OFF_LLH;

    hipMemsetAsync(tok, 0, CDIM * sizeof(float), stream);  // tok_enc row 0 = zeros
    pad_w_k<<<768, 64, 0, stream>>>(w_ih_l0, wpad);
    char_conv_k<<<NW / 8, 256, 0, stream>>>(char_emb, conv_w, conv_b, bcw, tok);
    build_texts_k<<<NPOS, 128, 0, stream>>>(word_emb, tok, btok, bcwi, texts);
    gemm_xg_k<<<dim3(768 / GBN, NPOS / GBM), 256, 0, stream>>>(texts, wpad, b_ih_l0, xg, IN0P);
    gru_rec_k<<<2 * BATCH, 512, 0, stream>>>(xg, w_hh_l0, b_hh_l0, blen, h0);
    gemm_xg_k<<<dim3(768 / GBN, NPOS / GBM), 256, 0, stream>>>(h0, w_ih_l1, b_ih_l1, xg, IN1);
    gru_rec_k<<<2 * BATCH, 512, 0, stream>>>(xg, w_hh_l1, b_hh_l1, blen, h1);
    mlp_emis_k<<<NPOS / 8, 128, 0, stream>>>(h1, mlp_w1, mlp_b1, mlp_w2, mlp_b2, emis);
    crf_k<<<BATCH, 64, 0, stream>>>(emis, crf_start, crf_end, crf_trans, target, blen, llh);
    finalize_k<<<1, 64, 0, stream>>>(llh, blen, (float*)d_out);
}